// Round 3
// baseline (236.959 us; speedup 1.0000x reference)
//
#include <hip/hip_runtime.h>
#include <hip/hip_bf16.h>

// CrossModalContrastiveLoss: B=8, C=256, H=W=32 -> N=8192 vectors of dim 256.
// loss = -( P - 1024 * sum_i log(sum_j exp(S_ij)) ) / 8388608,
// S = normalize(rgb) @ normalize(x)^T / 0.1, P = sum over positive mask
// (positive: col%8 == row/1024). Fused: S never materialized.

#define HWsz 1024
#define Cdim 256
#define Nvec 8192
#define CHW  (Cdim * HWsz)
#define NBLK 2048   // 32 x 64 gemm blocks

typedef __attribute__((ext_vector_type(8))) short bf16x8;
typedef __attribute__((ext_vector_type(4))) float f32x4;

__device__ inline unsigned short f2bf(float f) {
  unsigned int u = __float_as_uint(f);
  u += 0x7FFFu + ((u >> 16) & 1u);   // round-to-nearest-even
  return (unsigned short)(u >> 16);
}

// 32 vectors per block, C split 8 ways (32 channels/thread, cached in regs).
// Reads: 128-B contiguous runs per half-wave. Writes: staged through a padded
// LDS tile, then streamed out as full 512-B contiguous rows (coalesced).
__global__ __launch_bounds__(256) void norm_kernel(
    const float* __restrict__ rgb, const float* __restrict__ x,
    unsigned short* __restrict__ rgbn, unsigned short* __restrict__ xn) {
  __shared__ float ssp[8][32];
  __shared__ unsigned short tile[32][264];  // 264 = 256 + 8 pad (bank spread)
  const int t = threadIdx.x;
  const int nl = t & 31;        // vector within block
  const int part = t >> 5;      // 0..7: channel chunk
  const float* src = (blockIdx.y == 0) ? rgb : x;
  unsigned short* dst = (blockIdx.y == 0) ? rgbn : xn;
  const int n0 = blockIdx.x * 32;
  const int n = n0 + nl;
  const int b = n >> 10;
  const int hw = n & 1023;
  const float* p = src + (size_t)b * CHW + (size_t)(part * 32) * HWsz + hw;

  float v[32];
  float ss = 0.f;
#pragma unroll
  for (int j = 0; j < 32; ++j) {
    v[j] = p[(size_t)j * HWsz];
    ss += v[j] * v[j];
  }
  ssp[part][nl] = ss;
  __syncthreads();
  float tot = 0.f;
#pragma unroll
  for (int q = 0; q < 8; ++q) tot += ssp[q][nl];
  const float inv = 1.0f / fmaxf(sqrtf(tot), 1e-12f);

#pragma unroll
  for (int c0 = 0; c0 < 32; c0 += 8) {
    unsigned short tmp[8];
#pragma unroll
    for (int j = 0; j < 8; ++j) tmp[j] = f2bf(v[c0 + j] * inv);
    *reinterpret_cast<uint4*>(&tile[nl][part * 32 + c0]) =
        *reinterpret_cast<const uint4*>(tmp);
  }
  __syncthreads();

  // coalesced store: 4 passes x (8 rows x 512 B), consecutive lanes write
  // consecutive 16-B chunks within a row.
#pragma unroll
  for (int pass = 0; pass < 4; ++pass) {
    const int r = pass * 8 + (t >> 5);
    const int ck = (t & 31) * 8;
    *reinterpret_cast<uint4*>(dst + (size_t)(n0 + r) * Cdim + ck) =
        *reinterpret_cast<const uint4*>(&tile[r][ck]);
  }
}

// 256x128 tile NT GEMM (A=(N,C) rgb_n, B=(N,C) x_n row-major, K=256), 8 waves
// in 4x2 (wave tile 64x64, 4x4 acc of 16x16x32 MFMA). XOR-swizzled LDS:
// LDS[row][cg] holds global k-group cg ^ (row&7) (cg = 16-B unit), keeping
// global_load_lds's lane-contiguity while making frag reads conflict-free.
// Fused epilogue: exp-rowsum + positive-sum; last block computes the loss.
__global__ __launch_bounds__(512, 5) void gemm_loss_kernel(
    const unsigned short* __restrict__ A, const unsigned short* __restrict__ Bm,
    float* __restrict__ sumexp, float* __restrict__ Pacc,
    unsigned int* __restrict__ done, float* __restrict__ out) {
  __shared__ unsigned short sA[256 * 64];  // 32 KB
  __shared__ unsigned short sB[128 * 64];  // 16 KB
  __shared__ float rows_exp[256];
  __shared__ float pos_s;
  __shared__ float part8[8];
  __shared__ unsigned int is_last;

  const int tid  = threadIdx.x;
  const int lane = tid & 63;
  const int w    = tid >> 6;   // wave id 0..7
  const int wm   = w & 3;      // row quarter (64 rows)
  const int wn   = w >> 2;     // col half   (64 cols)
  const int brow = blockIdx.x; // 0..31 (256-row tiles)
  const int bcol = blockIdx.y; // 0..63 (128-col tiles)

  if (tid < 256) rows_exp[tid] = 0.f;
  if (tid == 0) pos_s = 0.f;

  f32x4 acc[4][4];
#pragma unroll
  for (int i = 0; i < 4; ++i)
#pragma unroll
    for (int j = 0; j < 4; ++j) acc[i][j] = (f32x4){0.f, 0.f, 0.f, 0.f};

  const int srow = tid >> 3;                        // 0..63 per 64-row group
  const int scol = (((tid & 7) ^ (srow & 7)) * 8);  // swizzled k-offset

  for (int kc = 0; kc < 4; ++kc) {
    const int k0 = kc * 64;
#pragma unroll
    for (int s = 0; s < 4; ++s) {  // A: 4 x 64 rows
      const unsigned short* gp =
          A + (size_t)(brow * 256 + s * 64 + srow) * Cdim + k0 + scol;
      unsigned short* lp = &sA[(s * 64 + w * 8) * 64];  // wave-uniform base
      __builtin_amdgcn_global_load_lds(
          (const __attribute__((address_space(1))) void*)gp,
          (__attribute__((address_space(3))) void*)lp, 16, 0, 0);
    }
#pragma unroll
    for (int s = 0; s < 2; ++s) {  // B: 2 x 64 rows
      const unsigned short* gp =
          Bm + (size_t)(bcol * 128 + s * 64 + srow) * Cdim + k0 + scol;
      unsigned short* lp = &sB[(s * 64 + w * 8) * 64];
      __builtin_amdgcn_global_load_lds(
          (const __attribute__((address_space(1))) void*)gp,
          (__attribute__((address_space(3))) void*)lp, 16, 0, 0);
    }
    __syncthreads();

#pragma unroll
    for (int ks = 0; ks < 2; ++ks) {
      const int cg = ((ks * 4 + (lane >> 4)) ^ (lane & 7)) * 8;
      bf16x8 af[4], bfr[4];
#pragma unroll
      for (int mi = 0; mi < 4; ++mi) {
        const int row = wm * 64 + mi * 16 + (lane & 15);
        af[mi] = *reinterpret_cast<const bf16x8*>(&sA[row * 64 + cg]);
      }
#pragma unroll
      for (int ni = 0; ni < 4; ++ni) {
        const int col = wn * 64 + ni * 16 + (lane & 15);
        bfr[ni] = *reinterpret_cast<const bf16x8*>(&sB[col * 64 + cg]);
      }
#pragma unroll
      for (int mi = 0; mi < 4; ++mi)
#pragma unroll
        for (int ni = 0; ni < 4; ++ni)
          acc[mi][ni] = __builtin_amdgcn_mfma_f32_16x16x32_bf16(
              af[mi], bfr[ni], acc[mi][ni], 0, 0, 0);
    }
    __syncthreads();
  }

  // ---- fused epilogue: exp row-sums + positive sum ----
  const float scale = 10.0f;                 // 1 / TEMPERATURE
  const int bsel = brow >> 2;                // global_row/1024, block-constant
  const bool ispos = ((lane & 7) == bsel);   // col%8 == lane&7
  const int q = lane >> 4;
  float posloc = 0.f;

#pragma unroll
  for (int mi = 0; mi < 4; ++mi) {
#pragma unroll
    for (int r = 0; r < 4; ++r) {
      float se = 0.f;
#pragma unroll
      for (int ni = 0; ni < 4; ++ni) {
        const float v = scale * acc[mi][ni][r];
        se += __expf(v);
        if (ispos) posloc += v;
      }
      se += __shfl_xor(se, 1);
      se += __shfl_xor(se, 2);
      se += __shfl_xor(se, 4);
      se += __shfl_xor(se, 8);
      if ((lane & 15) == 0)
        atomicAdd(&rows_exp[wm * 64 + mi * 16 + q * 4 + r], se);
    }
  }
  posloc += __shfl_xor(posloc, 1);
  posloc += __shfl_xor(posloc, 2);
  posloc += __shfl_xor(posloc, 4);
  posloc += __shfl_xor(posloc, 8);
  posloc += __shfl_xor(posloc, 16);
  posloc += __shfl_xor(posloc, 32);
  if (lane == 0) atomicAdd(&pos_s, posloc);
  __syncthreads();

  if (tid < 256) atomicAdd(&sumexp[brow * 256 + tid], rows_exp[tid]);
  if (tid == 0) atomicAdd(Pacc, pos_s);

  // ---- last block finalizes the loss ----
  if (tid == 0) {
    __threadfence();
    is_last = (atomicAdd(done, 1u) == NBLK - 1) ? 1u : 0u;
  }
  __syncthreads();
  if (is_last) {
    __threadfence();  // acquire: all blocks' sumexp/Pacc atomics visible
    float lsum = 0.f;
    for (int i = tid; i < Nvec; i += 512) lsum += logf(sumexp[i]);
    lsum += __shfl_xor(lsum, 1);
    lsum += __shfl_xor(lsum, 2);
    lsum += __shfl_xor(lsum, 4);
    lsum += __shfl_xor(lsum, 8);
    lsum += __shfl_xor(lsum, 16);
    lsum += __shfl_xor(lsum, 32);
    if ((tid & 63) == 0) part8[w] = lsum;
    __syncthreads();
    if (tid == 0) {
      float total_lse = 0.f;
#pragma unroll
      for (int i = 0; i < 8; ++i) total_lse += part8[i];
      const float P = Pacc[0];
      out[0] = -(P - 1024.0f * total_lse) / (8388608.0f + 1e-8f);
    }
  }
}

extern "C" void kernel_launch(void* const* d_in, const int* in_sizes, int n_in,
                              void* d_out, int out_size, void* d_ws,
                              size_t ws_size, hipStream_t stream) {
  const float* rgb = (const float*)d_in[0];
  const float* x   = (const float*)d_in[1];
  char* ws = (char*)d_ws;
  unsigned short* rgbn = (unsigned short*)ws;                            // 4 MiB
  unsigned short* xn   = (unsigned short*)(ws + (size_t)4 * 1024 * 1024);// 4 MiB
  float* sumexp = (float*)(ws + (size_t)8 * 1024 * 1024);                // 32 KiB
  float* Pacc   = sumexp + Nvec;
  unsigned int* done = (unsigned int*)(Pacc + 1);

  hipMemsetAsync(sumexp, 0, (Nvec + 4) * sizeof(float), stream);
  norm_kernel<<<dim3(256, 2), 256, 0, stream>>>(rgb, x, rgbn, xn);
  gemm_loss_kernel<<<dim3(32, 64), 512, 0, stream>>>(rgbn, xn, sumexp, Pacc,
                                                     done, (float*)d_out);
}

// Round 4
// 160.302 us; speedup vs baseline: 1.4782x; 1.4782x over previous
//
#include <hip/hip_runtime.h>
#include <hip/hip_bf16.h>

// CrossModalContrastiveLoss: B=8, C=256, H=W=32 -> N=8192 vectors of dim 256.
// loss = -( P - 1024 * sum_i log(sum_j exp(S_ij)) ) / 8388608,
// S = normalize(rgb) @ normalize(x)^T / 0.1, P = sum over positive mask
// (positive: col%8 == row/1024). S never materialized.
//
// Gemm structure (round 4): block owns 128 rows x 1024-col strip. A-panel
// (128x256) staged to LDS once, then held in REGISTERS (32 bf16x8 frags/wave,
// 128 VGPRs) for the whole block. B streamed in 4 stages of 256 cols through
// 128 KB LDS (XOR-swizzled per 64-short row-block, conflict-free - verified
// round 2). Row exp-sums accumulate in registers; one shuffle-reduce + global
// atomic per block. Last block finalizes the loss.

#define HWsz 1024
#define Cdim 256
#define Nvec 8192
#define CHW  (Cdim * HWsz)
#define NBLK 512   // 64 x 8 gemm blocks

typedef __attribute__((ext_vector_type(8))) short bf16x8;
typedef __attribute__((ext_vector_type(4))) float f32x4;

__device__ inline unsigned short f2bf(float f) {
  unsigned int u = __float_as_uint(f);
  u += 0x7FFFu + ((u >> 16) & 1u);   // round-to-nearest-even
  return (unsigned short)(u >> 16);
}

// 32 vectors per block, C split 8 ways (32 channels/thread, cached in regs).
// Also zero-inits sumexp/Pacc/done (replaces a memset dispatch).
__global__ __launch_bounds__(256) void norm_kernel(
    const float* __restrict__ rgb, const float* __restrict__ x,
    unsigned short* __restrict__ rgbn, unsigned short* __restrict__ xn,
    float* __restrict__ sumexp, float* __restrict__ Pacc,
    unsigned int* __restrict__ done) {
  __shared__ float ssp[8][32];
  __shared__ unsigned short tile[32][264];  // +8 pad
  const int t = threadIdx.x;
  const int nl = t & 31;        // vector within block
  const int part = t >> 5;      // 0..7: channel chunk
  const float* src = (blockIdx.y == 0) ? rgb : x;
  unsigned short* dst = (blockIdx.y == 0) ? rgbn : xn;
  const int n0 = blockIdx.x * 32;
  const int n = n0 + nl;
  const int b = n >> 10;
  const int hw = n & 1023;
  const float* p = src + (size_t)b * CHW + (size_t)(part * 32) * HWsz + hw;

  if (blockIdx.y == 0) {
    if (t < 32) sumexp[blockIdx.x * 32 + t] = 0.f;
    if (blockIdx.x == 0 && t == 0) { Pacc[0] = 0.f; done[0] = 0u; }
  }

  float v[32];
  float ss = 0.f;
#pragma unroll
  for (int j = 0; j < 32; ++j) {
    v[j] = p[(size_t)j * HWsz];
    ss += v[j] * v[j];
  }
  ssp[part][nl] = ss;
  __syncthreads();
  float tot = 0.f;
#pragma unroll
  for (int q = 0; q < 8; ++q) tot += ssp[q][nl];
  const float inv = 1.0f / fmaxf(sqrtf(tot), 1e-12f);

#pragma unroll
  for (int c0 = 0; c0 < 32; c0 += 8) {
    unsigned short tmp[8];
#pragma unroll
    for (int j = 0; j < 8; ++j) tmp[j] = f2bf(v[c0 + j] * inv);
    *reinterpret_cast<uint4*>(&tile[nl][part * 32 + c0]) =
        *reinterpret_cast<const uint4*>(tmp);
  }
  __syncthreads();

#pragma unroll
  for (int pass = 0; pass < 4; ++pass) {
    const int r = pass * 8 + (t >> 5);
    const int ck = (t & 31) * 8;
    *reinterpret_cast<uint4*>(dst + (size_t)(n0 + r) * Cdim + ck) =
        *reinterpret_cast<const uint4*>(&tile[r][ck]);
  }
}

__global__ __launch_bounds__(512, 2) void gemm_loss_kernel(
    const unsigned short* __restrict__ A, const unsigned short* __restrict__ Bm,
    float* __restrict__ sumexp, float* __restrict__ Pacc,
    unsigned int* __restrict__ done, float* __restrict__ out) {
  // Single 128 KB buffer: phase 1 holds A tile (64 KB, 4 kc x 128 rows x 64
  // shorts), then reused for B stages (4 kc x 256 cols x 64 shorts).
  __shared__ unsigned short s[4 * 256 * 64];
  __shared__ float part8[8];
  __shared__ unsigned int is_last;

  const int tid  = threadIdx.x;
  const int lane = tid & 63;
  const int w    = tid >> 6;   // wave 0..7
  const int wm   = w & 1;      // row half (64 rows)
  const int wn   = w >> 1;     // col slot (64 of 256 stage cols)
  const int rg   = blockIdx.x; // 0..63: rows rg*128..+128
  const int strip = blockIdx.y; // 0..7: cols strip*1024..+1024

  const int srow = tid >> 3;                        // 0..63
  const int scol = (((tid & 7) ^ (srow & 7)) * 8);  // swizzled k-offset
  const int quad = lane >> 4;
  const int l15  = lane & 15;

  // ---- phase 1: stage A (128 x 256) and lift to registers ----
#pragma unroll
  for (int kc = 0; kc < 4; ++kc)
#pragma unroll
    for (int sg = 0; sg < 2; ++sg) {
      const unsigned short* gp =
          A + (size_t)(rg * 128 + sg * 64 + srow) * Cdim + kc * 64 + scol;
      unsigned short* lp = &s[(kc * 128 + sg * 64 + w * 8) * 64];
      __builtin_amdgcn_global_load_lds(
          (const __attribute__((address_space(1))) void*)gp,
          (__attribute__((address_space(3))) void*)lp, 16, 0, 0);
    }
  __syncthreads();

  bf16x8 areg[4][2][4];  // [kc][ks][mi] : 128 VGPRs, reused for all 8192 cols
#pragma unroll
  for (int kc = 0; kc < 4; ++kc)
#pragma unroll
    for (int ks = 0; ks < 2; ++ks) {
      const int cg = ((ks * 4 + quad) ^ (lane & 7)) * 8;
#pragma unroll
      for (int mi = 0; mi < 4; ++mi) {
        const int row = wm * 64 + mi * 16 + l15;
        areg[kc][ks][mi] =
            *reinterpret_cast<const bf16x8*>(&s[(kc * 128 + row) * 64 + cg]);
      }
    }
  __syncthreads();

  const float scale = 10.0f;                 // 1 / TEMPERATURE
  const int bsel = rg >> 3;                  // row/1024, block-constant
  const bool ispos = ((lane & 7) == bsel);   // col%8 == lane&7
  float rowexp[16];
#pragma unroll
  for (int i = 0; i < 16; ++i) rowexp[i] = 0.f;
  float posloc = 0.f;

  // ---- phase 2: stream B in 4 stages of 256 cols ----
  for (int st = 0; st < 4; ++st) {
#pragma unroll
    for (int kc = 0; kc < 4; ++kc)
#pragma unroll
      for (int g = 0; g < 4; ++g) {
        const int j = strip * 1024 + st * 256 + g * 64 + srow;
        const unsigned short* gp =
            Bm + (size_t)j * Cdim + kc * 64 + scol;
        unsigned short* lp = &s[(kc * 256 + g * 64 + w * 8) * 64];
        __builtin_amdgcn_global_load_lds(
            (const __attribute__((address_space(1))) void*)gp,
            (__attribute__((address_space(3))) void*)lp, 16, 0, 0);
      }
    __syncthreads();

#pragma unroll
    for (int h = 0; h < 2; ++h) {   // 2 col-halves of 32 -> acc stays 32 regs
      f32x4 acc[4][2];
#pragma unroll
      for (int mi = 0; mi < 4; ++mi)
#pragma unroll
        for (int ni = 0; ni < 2; ++ni) acc[mi][ni] = (f32x4){0.f, 0.f, 0.f, 0.f};

#pragma unroll
      for (int kc = 0; kc < 4; ++kc)
#pragma unroll
        for (int ks = 0; ks < 2; ++ks) {
          const int cg = ((ks * 4 + quad) ^ (lane & 7)) * 8;
          bf16x8 bfr[2];
#pragma unroll
          for (int ni = 0; ni < 2; ++ni) {
            const int col = wn * 64 + h * 32 + ni * 16 + l15;
            bfr[ni] =
                *reinterpret_cast<const bf16x8*>(&s[(kc * 256 + col) * 64 + cg]);
          }
#pragma unroll
          for (int mi = 0; mi < 4; ++mi)
#pragma unroll
            for (int ni = 0; ni < 2; ++ni)
              acc[mi][ni] = __builtin_amdgcn_mfma_f32_16x16x32_bf16(
                  areg[kc][ks][mi], bfr[ni], acc[mi][ni], 0, 0, 0);
        }

      // accumulate exp row-sums + positive sum in registers
#pragma unroll
      for (int mi = 0; mi < 4; ++mi)
#pragma unroll
        for (int ni = 0; ni < 2; ++ni)
#pragma unroll
          for (int r = 0; r < 4; ++r) {
            const float v = scale * acc[mi][ni][r];
            rowexp[mi * 4 + r] += __expf(v);
            if (ispos) posloc += v;
          }
    }
    __syncthreads();  // B buffer reuse for next stage
  }

  // ---- block epilogue: one reduce + atomic per row slot ----
#pragma unroll
  for (int idx = 0; idx < 16; ++idx) {
    float se = rowexp[idx];
    se += __shfl_xor(se, 1);
    se += __shfl_xor(se, 2);
    se += __shfl_xor(se, 4);
    se += __shfl_xor(se, 8);
    if (l15 == 0) {
      const int row = rg * 128 + wm * 64 + (idx >> 2) * 16 + quad * 4 + (idx & 3);
      atomicAdd(&sumexp[row], se);
    }
  }
  posloc += __shfl_xor(posloc, 1);
  posloc += __shfl_xor(posloc, 2);
  posloc += __shfl_xor(posloc, 4);
  posloc += __shfl_xor(posloc, 8);
  posloc += __shfl_xor(posloc, 16);
  posloc += __shfl_xor(posloc, 32);
  if (lane == 0) atomicAdd(Pacc, posloc);

  // ---- last block finalizes the loss ----
  if (tid == 0) {
    __threadfence();
    is_last = (atomicAdd(done, 1u) == NBLK - 1) ? 1u : 0u;
  }
  __syncthreads();
  if (is_last) {
    __threadfence();  // acquire: all blocks' sumexp/Pacc atomics visible
    float lsum = 0.f;
    for (int i = tid; i < Nvec; i += 512) lsum += logf(sumexp[i]);
    lsum += __shfl_xor(lsum, 1);
    lsum += __shfl_xor(lsum, 2);
    lsum += __shfl_xor(lsum, 4);
    lsum += __shfl_xor(lsum, 8);
    lsum += __shfl_xor(lsum, 16);
    lsum += __shfl_xor(lsum, 32);
    if ((tid & 63) == 0) part8[w] = lsum;
    __syncthreads();
    if (tid == 0) {
      float total_lse = 0.f;
#pragma unroll
      for (int i = 0; i < 8; ++i) total_lse += part8[i];
      const float P = Pacc[0];
      out[0] = -(P - 1024.0f * total_lse) / (8388608.0f + 1e-8f);
    }
  }
}

extern "C" void kernel_launch(void* const* d_in, const int* in_sizes, int n_in,
                              void* d_out, int out_size, void* d_ws,
                              size_t ws_size, hipStream_t stream) {
  const float* rgb = (const float*)d_in[0];
  const float* x   = (const float*)d_in[1];
  char* ws = (char*)d_ws;
  unsigned short* rgbn = (unsigned short*)ws;                            // 4 MiB
  unsigned short* xn   = (unsigned short*)(ws + (size_t)4 * 1024 * 1024);// 4 MiB
  float* sumexp = (float*)(ws + (size_t)8 * 1024 * 1024);                // 32 KiB
  float* Pacc   = sumexp + Nvec;
  unsigned int* done = (unsigned int*)(Pacc + 1);

  norm_kernel<<<dim3(256, 2), 256, 0, stream>>>(rgb, x, rgbn, xn,
                                                sumexp, Pacc, done);
  gemm_loss_kernel<<<dim3(64, 8), 512, 0, stream>>>(rgbn, xn, sumexp, Pacc,
                                                    done, (float*)d_out);
}

// Round 6
// 136.861 us; speedup vs baseline: 1.7314x; 1.1713x over previous
//
#include <hip/hip_runtime.h>
#include <hip/hip_bf16.h>

// CrossModalContrastiveLoss: B=8, C=256, H=W=32 -> N=8192 vectors of dim 256.
// loss = -( P - 1024 * sum_i log(sum_j exp(S_ij)) ) / 8388608,
// S = normalize(rgb) @ normalize(x)^T / 0.1, positive: col%8 == row/1024.
// S never materialized.
//
// Round-6 gemm structure (round-5 + exp2 builtin fix): block = 512 rows x
// 512 cols. A-fragments loaded DIRECTLY from global into 128 regs/wave
// (coalesced: 16 full 64-B lines per wave-load) - no A staging, no A
// barriers. B streamed as 8 chunks of 64 cols x 256 k through
// DOUBLE-BUFFERED 2x32 KB LDS (XOR-swizzled, conflict-free, proven rounds
// 2-4): prefetch chunk c+1 issued before compute of chunk c, so the
// barrier's vmcnt(0) drain overlaps ~5K cycles of MFMA. One barrier per
// chunk. Row exp-sums accumulate in registers across all chunks; one
// shuffle-reduce + atomic per block. Last block finalizes the loss.

#define HWsz 1024
#define Cdim 256
#define Nvec 8192
#define CHW  (Cdim * HWsz)
#define NBLK 256   // 16 rowgroups x 16 colstrips

typedef __attribute__((ext_vector_type(8))) short bf16x8;
typedef __attribute__((ext_vector_type(4))) float f32x4;

__device__ inline unsigned short f2bf(float f) {
  unsigned int u = __float_as_uint(f);
  u += 0x7FFFu + ((u >> 16) & 1u);   // round-to-nearest-even
  return (unsigned short)(u >> 16);
}

// 32 vectors per block, C split 8 ways (32 channels/thread, cached in regs).
// Also zero-inits sumexp/Pacc/done (replaces a memset dispatch).
__global__ __launch_bounds__(256) void norm_kernel(
    const float* __restrict__ rgb, const float* __restrict__ x,
    unsigned short* __restrict__ rgbn, unsigned short* __restrict__ xn,
    float* __restrict__ sumexp, float* __restrict__ Pacc,
    unsigned int* __restrict__ done) {
  __shared__ float ssp[8][32];
  __shared__ unsigned short tile[32][264];  // +8 pad
  const int t = threadIdx.x;
  const int nl = t & 31;        // vector within block
  const int part = t >> 5;      // 0..7: channel chunk
  const float* src = (blockIdx.y == 0) ? rgb : x;
  unsigned short* dst = (blockIdx.y == 0) ? rgbn : xn;
  const int n0 = blockIdx.x * 32;
  const int n = n0 + nl;
  const int b = n >> 10;
  const int hw = n & 1023;
  const float* p = src + (size_t)b * CHW + (size_t)(part * 32) * HWsz + hw;

  if (blockIdx.y == 0) {
    if (t < 32) sumexp[blockIdx.x * 32 + t] = 0.f;
    if (blockIdx.x == 0 && t == 0) { Pacc[0] = 0.f; done[0] = 0u; }
  }

  float v[32];
  float ss = 0.f;
#pragma unroll
  for (int j = 0; j < 32; ++j) {
    v[j] = p[(size_t)j * HWsz];
    ss += v[j] * v[j];
  }
  ssp[part][nl] = ss;
  __syncthreads();
  float tot = 0.f;
#pragma unroll
  for (int q = 0; q < 8; ++q) tot += ssp[q][nl];
  const float inv = 1.0f / fmaxf(sqrtf(tot), 1e-12f);

#pragma unroll
  for (int c0 = 0; c0 < 32; c0 += 8) {
    unsigned short tmp[8];
#pragma unroll
    for (int j = 0; j < 8; ++j) tmp[j] = f2bf(v[c0 + j] * inv);
    *reinterpret_cast<uint4*>(&tile[nl][part * 32 + c0]) =
        *reinterpret_cast<const uint4*>(tmp);
  }
  __syncthreads();

#pragma unroll
  for (int pass = 0; pass < 4; ++pass) {
    const int r = pass * 8 + (t >> 5);
    const int ck = (t & 31) * 8;
    *reinterpret_cast<uint4*>(dst + (size_t)(n0 + r) * Cdim + ck) =
        *reinterpret_cast<const uint4*>(&tile[r][ck]);
  }
}

__global__ __launch_bounds__(512, 2) void gemm_loss_kernel(
    const unsigned short* __restrict__ A, const unsigned short* __restrict__ Bm,
    float* __restrict__ sumexp, float* __restrict__ Pacc,
    unsigned int* __restrict__ done, float* __restrict__ out) {
  // Double-buffered B chunk: [buf][(kc*64 + col)*64 + swizzled-k] (32 KB each).
  // LDS slot (col, j) holds global k-group j ^ (col&7) within its kc.
  __shared__ unsigned short sB[2][64 * 256];
  __shared__ float part8[8];
  __shared__ unsigned int is_last;

  const int tid  = threadIdx.x;
  const int lane = tid & 63;
  const int w    = tid >> 6;      // wave 0..7 -> rows w*64..+64
  const int rg   = blockIdx.x;    // 0..15: rows rg*512..+512
  const int strip = blockIdx.y;   // 0..15: cols strip*512..+512
  const int quad = lane >> 4;
  const int l15  = lane & 15;

  // ---- A fragments: direct global -> regs (AGPR-backed), once per block ----
  // areg[s][mi]: rows rg*512 + w*64 + mi*16 + l15, k-bytes s*64 + quad*16.
  bf16x8 areg[8][4];
#pragma unroll
  for (int mi = 0; mi < 4; ++mi) {
    const unsigned short* rp =
        A + (size_t)(rg * 512 + w * 64 + mi * 16 + l15) * Cdim + quad * 8;
#pragma unroll
    for (int s = 0; s < 8; ++s)
      areg[s][mi] = *reinterpret_cast<const bf16x8*>(rp + s * 32);
  }

  // staging indices (proven swizzle from rounds 2-4)
  const int srowc = tid >> 3;                            // col-in-chunk 0..63
  const int sgrp  = ((tid & 7) ^ (srowc & 7)) * 8;       // swizzled k-group

  const int bsel = rg >> 1;                  // row/1024, block-constant
  const bool ispos = ((lane & 7) == bsel);   // col%8 == lane&7
  float rowexp[16];
#pragma unroll
  for (int i = 0; i < 16; ++i) rowexp[i] = 0.f;
  float posraw = 0.f;

  // prefetch chunk 0 into buf 0
#pragma unroll
  for (int kc = 0; kc < 4; ++kc) {
    const unsigned short* gp =
        Bm + (size_t)(strip * 512 + srowc) * Cdim + kc * 64 + sgrp;
    unsigned short* lp = &sB[0][(kc * 64 + w * 8) * 64];  // + lane*16 by HW
    __builtin_amdgcn_global_load_lds(
        (const __attribute__((address_space(1))) void*)gp,
        (__attribute__((address_space(3))) void*)lp, 16, 0, 0);
  }
  __syncthreads();

  const float k2 = 14.4269504089f;  // (1/T) * log2(e)

  for (int c = 0; c < 8; ++c) {
    const int bf = c & 1;
    if (c < 7) {  // prefetch next chunk into the other buffer (overlaps MFMA)
#pragma unroll
      for (int kc = 0; kc < 4; ++kc) {
        const unsigned short* gp =
            Bm + (size_t)(strip * 512 + (c + 1) * 64 + srowc) * Cdim +
            kc * 64 + sgrp;
        unsigned short* lp = &sB[bf ^ 1][(kc * 64 + w * 8) * 64];
        __builtin_amdgcn_global_load_lds(
            (const __attribute__((address_space(1))) void*)gp,
            (__attribute__((address_space(3))) void*)lp, 16, 0, 0);
      }
    }

    // compute 64x64-wave-tile x 64 cols of this chunk
    f32x4 acc[4][4];
#pragma unroll
    for (int mi = 0; mi < 4; ++mi)
#pragma unroll
      for (int ni = 0; ni < 4; ++ni) acc[mi][ni] = (f32x4){0.f, 0.f, 0.f, 0.f};

#pragma unroll
    for (int s = 0; s < 8; ++s) {
      const int kc = s >> 1;
      const int g = (s & 1) * 4 + quad;
      bf16x8 bfr[4];
#pragma unroll
      for (int ni = 0; ni < 4; ++ni) {
        const int col = ni * 16 + l15;
        bfr[ni] = *reinterpret_cast<const bf16x8*>(
            &sB[bf][(kc * 64 + col) * 64 + ((g ^ (l15 & 7)) * 8)]);
      }
#pragma unroll
      for (int mi = 0; mi < 4; ++mi)
#pragma unroll
        for (int ni = 0; ni < 4; ++ni)
          acc[mi][ni] = __builtin_amdgcn_mfma_f32_16x16x32_bf16(
              areg[s][mi], bfr[ni], acc[mi][ni], 0, 0, 0);
    }

    // accumulate exp row-sums (exp(10*t) = exp2(t*14.427)) + raw positive sum
#pragma unroll
    for (int mi = 0; mi < 4; ++mi)
#pragma unroll
      for (int ni = 0; ni < 4; ++ni)
#pragma unroll
        for (int r = 0; r < 4; ++r) {
          const float t = acc[mi][ni][r];
          rowexp[mi * 4 + r] += __builtin_amdgcn_exp2f(t * k2);
          if (ispos) posraw += t;
        }

    __syncthreads();  // guards buffer reuse; drains (mostly-landed) prefetch
  }

  // ---- block epilogue: one reduce + atomic per row slot ----
#pragma unroll
  for (int idx = 0; idx < 16; ++idx) {
    float se = rowexp[idx];
    se += __shfl_xor(se, 1);
    se += __shfl_xor(se, 2);
    se += __shfl_xor(se, 4);
    se += __shfl_xor(se, 8);
    if (l15 == 0) {
      const int row = rg * 512 + w * 64 + (idx >> 2) * 16 + quad * 4 + (idx & 3);
      atomicAdd(&sumexp[row], se);
    }
  }
  float posloc = posraw * 10.0f;
  posloc += __shfl_xor(posloc, 1);
  posloc += __shfl_xor(posloc, 2);
  posloc += __shfl_xor(posloc, 4);
  posloc += __shfl_xor(posloc, 8);
  posloc += __shfl_xor(posloc, 16);
  posloc += __shfl_xor(posloc, 32);
  if (lane == 0) atomicAdd(Pacc, posloc);

  // ---- last block finalizes the loss ----
  if (tid == 0) {
    __threadfence();
    is_last = (atomicAdd(done, 1u) == NBLK - 1) ? 1u : 0u;
  }
  __syncthreads();
  if (is_last) {
    __threadfence();  // acquire: all blocks' sumexp/Pacc atomics visible
    float lsum = 0.f;
    for (int i = tid; i < Nvec; i += 512) lsum += logf(sumexp[i]);
    lsum += __shfl_xor(lsum, 1);
    lsum += __shfl_xor(lsum, 2);
    lsum += __shfl_xor(lsum, 4);
    lsum += __shfl_xor(lsum, 8);
    lsum += __shfl_xor(lsum, 16);
    lsum += __shfl_xor(lsum, 32);
    if ((tid & 63) == 0) part8[w] = lsum;
    __syncthreads();
    if (tid == 0) {
      float total_lse = 0.f;
#pragma unroll
      for (int i = 0; i < 8; ++i) total_lse += part8[i];
      const float P = Pacc[0];
      out[0] = -(P - 1024.0f * total_lse) / (8388608.0f + 1e-8f);
    }
  }
}

extern "C" void kernel_launch(void* const* d_in, const int* in_sizes, int n_in,
                              void* d_out, int out_size, void* d_ws,
                              size_t ws_size, hipStream_t stream) {
  const float* rgb = (const float*)d_in[0];
  const float* x   = (const float*)d_in[1];
  char* ws = (char*)d_ws;
  unsigned short* rgbn = (unsigned short*)ws;                            // 4 MiB
  unsigned short* xn   = (unsigned short*)(ws + (size_t)4 * 1024 * 1024);// 4 MiB
  float* sumexp = (float*)(ws + (size_t)8 * 1024 * 1024);                // 32 KiB
  float* Pacc   = sumexp + Nvec;
  unsigned int* done = (unsigned int*)(Pacc + 1);

  norm_kernel<<<dim3(256, 2), 256, 0, stream>>>(rgb, x, rgbn, xn,
                                                sumexp, Pacc, done);
  gemm_loss_kernel<<<dim3(16, 16), 512, 0, stream>>>(rgbn, xn, sumexp, Pacc,
                                                     done, (float*)d_out);
}

// Round 7
// 123.466 us; speedup vs baseline: 1.9192x; 1.1085x over previous
//
#include <hip/hip_runtime.h>
#include <hip/hip_bf16.h>

// CrossModalContrastiveLoss: B=8, C=256, H=W=32 -> N=8192 vectors of dim 256.
// loss = -( P - 1024 * sum_i log(sum_j exp(S_ij)) ) / 8388608,
// S = normalize(rgb) @ normalize(x)^T / 0.1.
// P computed analytically from per-batch sums: positives for row i are cols
// j with j%8 == i/1024, so P = 10 * sum_b (sum_{i in b} rgb_i).(sum_{j%8==b} x_j).
// S never materialized.
//
// Round-7 gemm: 256-thread blocks (4 waves, 256 rows x 512-col strip),
// 512 blocks = 2 independent blocks/CU so their chunk barriers interleave
// (round-6 ran 1 block/CU: every barrier drain idled the whole CU).
// A-fragments direct global->regs (128/wave, AGPR-backed). B double-buffered
// 2x32 KB LDS chunks (XOR-swizzled, conflict-free). Strips pinned to XCDs
// via blockIdx.x (XCD = (x + 16y) % 8 = x % 8).

#define HWsz 1024
#define Cdim 256
#define Nvec 8192
#define CHW  (Cdim * HWsz)
#define NBLK 512   // 16 strips x 32 rowgroups

typedef __attribute__((ext_vector_type(8))) short bf16x8;
typedef __attribute__((ext_vector_type(4))) float f32x4;

__device__ inline unsigned short f2bf(float f) {
  unsigned int u = __float_as_uint(f);
  u += 0x7FFFu + ((u >> 16) & 1u);   // round-to-nearest-even
  return (unsigned short)(u >> 16);
}

// 32 vectors per block (all one batch), C split 8 ways. Also accumulates the
// per-batch channel sums of the normalized bf16 vectors (for analytic P).
__global__ __launch_bounds__(256) void norm_kernel(
    const float* __restrict__ rgb, const float* __restrict__ x,
    unsigned short* __restrict__ rgbn, unsigned short* __restrict__ xn,
    float* __restrict__ bsums) {
  __shared__ float ssp[8][32];
  __shared__ unsigned short tile[32][264];  // +8 pad
  const int t = threadIdx.x;
  const int nl = t & 31;        // vector within block
  const int part = t >> 5;      // 0..7: channel chunk
  const float* src = (blockIdx.y == 0) ? rgb : x;
  unsigned short* dst = (blockIdx.y == 0) ? rgbn : xn;
  const int n0 = blockIdx.x * 32;
  const int n = n0 + nl;
  const int b = n >> 10;        // uniform per block (32 | 1024)
  const int hw = n & 1023;
  const float* p = src + (size_t)b * CHW + (size_t)(part * 32) * HWsz + hw;

  float v[32];
  float ss = 0.f;
#pragma unroll
  for (int j = 0; j < 32; ++j) {
    v[j] = p[(size_t)j * HWsz];
    ss += v[j] * v[j];
  }
  ssp[part][nl] = ss;
  __syncthreads();
  float tot = 0.f;
#pragma unroll
  for (int q = 0; q < 8; ++q) tot += ssp[q][nl];
  const float inv = 1.0f / fmaxf(sqrtf(tot), 1e-12f);

#pragma unroll
  for (int c0 = 0; c0 < 32; c0 += 8) {
    unsigned short tmp[8];
#pragma unroll
    for (int j = 0; j < 8; ++j) tmp[j] = f2bf(v[c0 + j] * inv);
    *reinterpret_cast<uint4*>(&tile[nl][part * 32 + c0]) =
        *reinterpret_cast<const uint4*>(tmp);
  }
  __syncthreads();

#pragma unroll
  for (int pass = 0; pass < 4; ++pass) {
    const int r = pass * 8 + (t >> 5);
    const int ck = (t & 31) * 8;
    *reinterpret_cast<uint4*>(dst + (size_t)(n0 + r) * Cdim + ck) =
        *reinterpret_cast<const uint4*>(&tile[r][ck]);
  }

  // per-channel column sum over this block's 32 vectors -> batch sums
  float csum = 0.f;
#pragma unroll
  for (int r = 0; r < 32; ++r)
    csum += __uint_as_float((unsigned int)tile[r][t] << 16);
  atomicAdd(&bsums[(blockIdx.y ? 2048 : 0) + b * 256 + t], csum);
}

__global__ __launch_bounds__(256, 2) void gemm_loss_kernel(
    const unsigned short* __restrict__ A, const unsigned short* __restrict__ Bm,
    float* __restrict__ sumexp, const float* __restrict__ bsums,
    unsigned int* __restrict__ done, float* __restrict__ out) {
  // Double-buffered B chunk: [buf][(kc*64 + col)*64 + swizzled-k] (32 KB each).
  // LDS slot (col, j) holds global k-group j ^ (col&7) within its kc.
  __shared__ unsigned short sB[2][64 * 256];
  __shared__ float part4[4], part4b[4];
  __shared__ unsigned int is_last;

  const int tid  = threadIdx.x;
  const int lane = tid & 63;
  const int w    = tid >> 6;      // wave 0..3 -> rows w*64..+64
  const int strip = blockIdx.x;   // 0..15: cols strip*512..+512 (XCD-pinned)
  const int rg   = blockIdx.y;    // 0..31: rows rg*256..+256
  const int quad = lane >> 4;
  const int l15  = lane & 15;

  // ---- A fragments: direct global -> regs (AGPR-backed), once per block ----
  bf16x8 areg[8][4];
#pragma unroll
  for (int mi = 0; mi < 4; ++mi) {
    const unsigned short* rp =
        A + (size_t)(rg * 256 + w * 64 + mi * 16 + l15) * Cdim + quad * 8;
#pragma unroll
    for (int s = 0; s < 8; ++s)
      areg[s][mi] = *reinterpret_cast<const bf16x8*>(rp + s * 32);
  }

  // staging indices (proven swizzle, rounds 2-6)
  const int srowc = tid >> 3;                            // col-in-pass 0..31
  const int sgrp  = ((tid & 7) ^ (srowc & 7)) * 8;       // swizzled k-group

  float rowexp[16];
#pragma unroll
  for (int i = 0; i < 16; ++i) rowexp[i] = 0.f;

  // prefetch chunk 0 into buf 0 (32 KB = 8 wave-instrs/wave over sg,kc)
#pragma unroll
  for (int sg = 0; sg < 2; ++sg)
#pragma unroll
    for (int kc = 0; kc < 4; ++kc) {
      const unsigned short* gp =
          Bm + (size_t)(strip * 512 + sg * 32 + srowc) * Cdim + kc * 64 + sgrp;
      unsigned short* lp = &sB[0][(kc * 64 + sg * 32 + w * 8) * 64];
      __builtin_amdgcn_global_load_lds(
          (const __attribute__((address_space(1))) void*)gp,
          (__attribute__((address_space(3))) void*)lp, 16, 0, 0);
    }
  __syncthreads();

  const float k2 = 14.4269504089f;  // (1/T) * log2(e)

  for (int c = 0; c < 8; ++c) {
    const int bf = c & 1;
    if (c < 7) {  // prefetch next chunk into the other buffer (overlaps MFMA)
#pragma unroll
      for (int sg = 0; sg < 2; ++sg)
#pragma unroll
        for (int kc = 0; kc < 4; ++kc) {
          const unsigned short* gp =
              Bm + (size_t)(strip * 512 + (c + 1) * 64 + sg * 32 + srowc) * Cdim +
              kc * 64 + sgrp;
          unsigned short* lp = &sB[bf ^ 1][(kc * 64 + sg * 32 + w * 8) * 64];
          __builtin_amdgcn_global_load_lds(
              (const __attribute__((address_space(1))) void*)gp,
              (__attribute__((address_space(3))) void*)lp, 16, 0, 0);
        }
    }

    f32x4 acc[4][4];
#pragma unroll
    for (int mi = 0; mi < 4; ++mi)
#pragma unroll
      for (int ni = 0; ni < 4; ++ni) acc[mi][ni] = (f32x4){0.f, 0.f, 0.f, 0.f};

#pragma unroll
    for (int s = 0; s < 8; ++s) {
      const int kc = s >> 1;
      const int g = (s & 1) * 4 + quad;
      bf16x8 bfr[4];
#pragma unroll
      for (int ni = 0; ni < 4; ++ni) {
        const int col = ni * 16 + l15;
        bfr[ni] = *reinterpret_cast<const bf16x8*>(
            &sB[bf][(kc * 64 + col) * 64 + ((g ^ (l15 & 7)) * 8)]);
      }
#pragma unroll
      for (int mi = 0; mi < 4; ++mi)
#pragma unroll
        for (int ni = 0; ni < 4; ++ni)
          acc[mi][ni] = __builtin_amdgcn_mfma_f32_16x16x32_bf16(
              areg[s][mi], bfr[ni], acc[mi][ni], 0, 0, 0);
    }

    // accumulate exp row-sums: exp(10*t) = exp2(t * 14.427)
#pragma unroll
    for (int mi = 0; mi < 4; ++mi)
#pragma unroll
      for (int ni = 0; ni < 4; ++ni)
#pragma unroll
        for (int r = 0; r < 4; ++r)
          rowexp[mi * 4 + r] += __builtin_amdgcn_exp2f(acc[mi][ni][r] * k2);

    __syncthreads();  // guards buffer reuse; prefetch had full compute to land
  }

  // ---- block epilogue: one reduce + atomic per row slot ----
#pragma unroll
  for (int idx = 0; idx < 16; ++idx) {
    float se = rowexp[idx];
    se += __shfl_xor(se, 1);
    se += __shfl_xor(se, 2);
    se += __shfl_xor(se, 4);
    se += __shfl_xor(se, 8);
    if (l15 == 0) {
      const int row = rg * 256 + w * 64 + (idx >> 2) * 16 + quad * 4 + (idx & 3);
      atomicAdd(&sumexp[row], se);
    }
  }

  // ---- last block finalizes the loss ----
  if (tid == 0) {
    __threadfence();
    is_last = (atomicAdd(done, 1u) == NBLK - 1) ? 1u : 0u;
  }
  __syncthreads();
  if (is_last) {
    __threadfence();  // acquire: all blocks' sumexp atomics visible
    float lsum = 0.f;
    for (int i = tid; i < Nvec; i += 256) lsum += logf(sumexp[i]);
    // analytic positive-sum: P = 10 * sum_b sum_c rgbsum[b][c]*xsum[b][c]
    float pp = 0.f;
#pragma unroll
    for (int b = 0; b < 8; ++b)
      pp += bsums[b * 256 + tid] * bsums[2048 + b * 256 + tid];
#pragma unroll
    for (int off = 1; off < 64; off <<= 1) {
      lsum += __shfl_xor(lsum, off);
      pp   += __shfl_xor(pp, off);
    }
    if ((tid & 63) == 0) { part4[w] = lsum; part4b[w] = pp; }
    __syncthreads();
    if (tid == 0) {
      float total_lse = 0.f, P = 0.f;
#pragma unroll
      for (int i = 0; i < 4; ++i) { total_lse += part4[i]; P += part4b[i]; }
      P *= 10.0f;
      out[0] = -(P - 1024.0f * total_lse) / (8388608.0f + 1e-8f);
    }
  }
}

extern "C" void kernel_launch(void* const* d_in, const int* in_sizes, int n_in,
                              void* d_out, int out_size, void* d_ws,
                              size_t ws_size, hipStream_t stream) {
  const float* rgb = (const float*)d_in[0];
  const float* x   = (const float*)d_in[1];
  char* ws = (char*)d_ws;
  unsigned short* rgbn = (unsigned short*)ws;                            // 4 MiB
  unsigned short* xn   = (unsigned short*)(ws + (size_t)4 * 1024 * 1024);// 4 MiB
  float* sumexp = (float*)(ws + (size_t)8 * 1024 * 1024);  // 8192 floats
  float* bsums  = sumexp + Nvec;                           // 2x8x256 floats
  unsigned int* done = (unsigned int*)(bsums + 4096);

  hipMemsetAsync(sumexp, 0, (Nvec + 4096 + 4) * sizeof(float), stream);
  norm_kernel<<<dim3(256, 2), 256, 0, stream>>>(rgb, x, rgbn, xn, bsums);
  gemm_loss_kernel<<<dim3(16, 32), 256, 0, stream>>>(rgbn, xn, sumexp, bsums,
                                                     done, (float*)d_out);
}